// Round 13
// baseline (327.224 us; speedup 1.0000x reference)
//
#include <hip/hip_runtime.h>

#define S_LEN 2048
#define HID   2048
#define NHEAD 16
#define HDIM  128
#define BATCH 2
#define KDIM  2048

using bf16x8  = __attribute__((ext_vector_type(8))) short;
using f32x4   = __attribute__((ext_vector_type(4))) float;
using short4v = __attribute__((ext_vector_type(4))) short;

__device__ __forceinline__ short f2bf(float f) {
  union { float f; unsigned u; } v; v.f = f;
  unsigned r = v.u + 0x7fffu + ((v.u >> 16) & 1u);
  return (short)(r >> 16);
}
__device__ __forceinline__ float bf2f(short s) {
  union { unsigned u; float f; } v;
  v.u = ((unsigned)(unsigned short)s) << 16;
  return v.f;
}

// async global->LDS, 16B per lane. LDS dest must be wave-uniform base + lane*16.
__device__ __forceinline__ void gl_lds16(const void* g, void* l) {
  __builtin_amdgcn_global_load_lds(
      (const __attribute__((address_space(1))) void*)g,
      (__attribute__((address_space(3))) void*)l, 16, 0, 0);
}

// ---------------- convert: hs, wq, wk, wv, wo  f32 -> bf16 -------------------
__global__ __launch_bounds__(256)
void convert_all(const float* __restrict__ hs, const float* __restrict__ wq,
                 const float* __restrict__ wk, const float* __restrict__ wv,
                 const float* __restrict__ wo,
                 short* __restrict__ hsb, short* __restrict__ wqkv,
                 short* __restrict__ wob)
{
  int i = blockIdx.x * 256 + threadIdx.x;
  const float* src; short* dst; int j = i;
  if (j < 1048576)      { src = hs; dst = hsb; }
  else if (j < 1572864) { j -= 1048576; src = wq; dst = wqkv; }
  else if (j < 2097152) { j -= 1572864; src = wk; dst = wqkv + 4194304; }
  else if (j < 2621440) { j -= 2097152; src = wv; dst = wqkv + 8388608; }
  else                  { j -= 2621440; src = wo; dst = wob; }
  f32x4 a = ((const f32x4*)src)[2 * j];
  f32x4 b = ((const f32x4*)src)[2 * j + 1];
  bf16x8 o;
  o[0]=f2bf(a[0]); o[1]=f2bf(a[1]); o[2]=f2bf(a[2]); o[3]=f2bf(a[3]);
  o[4]=f2bf(b[0]); o[5]=f2bf(b[1]); o[6]=f2bf(b[2]); o[7]=f2bf(b[3]);
  ((bf16x8*)dst)[j] = o;
}

// ---------------- bf16 GEMM, C = A @ B^T + bias (BK=64, swizzled; r11) -------
template<int KIND>
__global__ __launch_bounds__(256)
void gemm128(const short* __restrict__ A, const short* __restrict__ B,
             const float* __restrict__ bias0, const float* __restrict__ bias1,
             const float* __restrict__ bias2,
             void* __restrict__ O0, void* __restrict__ O1, void* __restrict__ O2)
{
  __shared__ __align__(16) short As[128 * 64];
  __shared__ __align__(16) short Bs[128 * 64];
  const int tid  = threadIdx.x;
  const int lane = tid & 63, wave = tid >> 6;
  const int ln = lane & 15, g = lane >> 4;
  const int wr = wave >> 1, wc = wave & 1;
  const int m0 = blockIdx.x * 128, n0 = blockIdx.y * 128;

  const int srow   = tid >> 3;
  const int schunk = (tid & 7) ^ (srow & 7);
  const short* aS = A + (size_t)(m0 + srow) * KDIM + schunk * 8;
  const short* bS = B + (size_t)(n0 + srow) * KDIM + schunk * 8;

  f32x4 acc[4][4] = {};

  for (int k0 = 0; k0 < KDIM; k0 += 64) {
    __syncthreads();
#pragma unroll
    for (int j = 0; j < 4; ++j) {
      gl_lds16(aS + k0 + j * (32 * KDIM), &As[j * 2048 + tid * 8]);
      gl_lds16(bS + k0 + j * (32 * KDIM), &Bs[j * 2048 + tid * 8]);
    }
    __syncthreads();

#pragma unroll
    for (int ks = 0; ks < 2; ++ks) {
      bf16x8 af[4], bfm[4];
#pragma unroll
      for (int i = 0; i < 4; ++i) {
        const int r = wr * 64 + i * 16 + ln;
        af[i] = *(const bf16x8*)&As[r * 64 + (((ks * 4 + g) ^ (r & 7)) << 3)];
      }
#pragma unroll
      for (int j2 = 0; j2 < 4; ++j2) {
        const int r = wc * 64 + j2 * 16 + ln;
        bfm[j2] = *(const bf16x8*)&Bs[r * 64 + (((ks * 4 + g) ^ (r & 7)) << 3)];
      }
#pragma unroll
      for (int i = 0; i < 4; ++i)
#pragma unroll
        for (int j2 = 0; j2 < 4; ++j2)
          acc[i][j2] = __builtin_amdgcn_mfma_f32_16x16x32_bf16(af[i], bfm[j2], acc[i][j2], 0, 0, 0);
    }
  }

  if constexpr (KIND == 0) {
    const int seg   = n0 >> 11;
    const int nbase = (n0 & 2047) + wc * 64;
    const float* bias = (seg == 0) ? bias0 : (seg == 1) ? bias1 : bias2;
    float bvv[4];
#pragma unroll
    for (int j = 0; j < 4; ++j) bvv[j] = bias[nbase + j * 16 + ln];
    if (seg < 2) {           // Q,K -> [b][h][s][d] bf16
      short* C = (short*)(seg ? O1 : O0);
#pragma unroll
      for (int i = 0; i < 4; ++i) {
        const int mb = m0 + wr * 64 + i * 16 + 4 * g;
#pragma unroll
        for (int j = 0; j < 4; ++j) {
          const int nl = nbase + j * 16 + ln;
          const int h = nl >> 7, d = nl & 127;
#pragma unroll
          for (int e = 0; e < 4; ++e) {
            const int m = mb + e, bb = m >> 11, t = m & (S_LEN - 1);
            C[((size_t)((bb * NHEAD + h) * S_LEN + t) << 7) + d] = f2bf(acc[i][j][e] + bvv[j]);
          }
        }
      }
    } else {                 // V -> transposed [b][h][d][s] bf16
      short* C = (short*)O2;
#pragma unroll
      for (int i = 0; i < 4; ++i) {
        const int mb = m0 + wr * 64 + i * 16 + 4 * g;
        const int bb = mb >> 11, t0 = mb & (S_LEN - 1);
#pragma unroll
        for (int j = 0; j < 4; ++j) {
          const int nl = nbase + j * 16 + ln;
          const int h = nl >> 7, d = nl & 127;
          short4v v;
#pragma unroll
          for (int e = 0; e < 4; ++e) v[e] = f2bf(acc[i][j][e] + bvv[j]);
          *(short4v*)&C[((size_t)((bb * NHEAD + h) * HDIM + d)) * S_LEN + t0] = v;
        }
      }
    }
  } else {                   // O-proj -> f32
    float* C = (float*)O0;
    float bvv[4];
#pragma unroll
    for (int j = 0; j < 4; ++j) bvv[j] = bias0[n0 + wc * 64 + j * 16 + ln];
#pragma unroll
    for (int i = 0; i < 4; ++i) {
      const int mb = m0 + wr * 64 + i * 16 + 4 * g;
#pragma unroll
      for (int j = 0; j < 4; ++j) {
        const int n = n0 + wc * 64 + j * 16 + ln;
#pragma unroll
        for (int e = 0; e < 4; ++e)
          C[(size_t)(mb + e) * HID + n] = acc[i][j][e] + bvv[j];
      }
    }
  }
}

// ---------------- RoPE in-place on Q,K ([b][h][s][d] bf16) -------------------
// Q additionally pre-scaled by 1/sqrt(HD)*log2(e): softmax runs in exp2 domain.
#define QSCALE 0.12752767502f   // (1/sqrt(128)) * log2(e)
__global__ __launch_bounds__(256)
void rope_kernel(short* __restrict__ Qb, short* __restrict__ Kb,
                 const int* __restrict__ pos_ids)
{
  const int row = blockIdx.x * 4 + (threadIdx.x >> 6);
  const int d   = threadIdx.x & 63;
  const int bh  = row >> 11, t = row & (S_LEN - 1);
  const int b   = bh >> 4;
  const float pos = (float)pos_ids[b * S_LEN + t];
  const float inv = powf(10000.0f, -(float)d * (1.0f / 64.0f));
  float s, c;
  sincosf(pos * inv, &s, &c);
  const size_t base = (size_t)row * HDIM;
  {
    float x1 = bf2f(Qb[base + d]), x2 = bf2f(Qb[base + d + 64]);
    Qb[base + d]      = f2bf((x1 * c - x2 * s) * QSCALE);
    Qb[base + d + 64] = f2bf((x2 * c + x1 * s) * QSCALE);
  }
  {
    float x1 = bf2f(Kb[base + d]), x2 = bf2f(Kb[base + d + 64]);
    Kb[base + d]      = f2bf(x1 * c - x2 * s);
    Kb[base + d + 64] = f2bf(x2 * c + x1 * s);
  }
}

// ---------------- flash attention ------------------------------------------
// r12 structure + CU-QUAD-BALANCED yt map. Dispatch model: CU(x,c) hosts bids
// {b, b+256, b+512, b+768} = groups {G, G+8, G+16, G+24}, same bh. Map those
// to yts {G, 15-G, 16+G, 31-G} -> per-CU iters {G+1,16-G,17+G,32-G} = 66 for
// every G (bijective on 0..31). Old zigzag left some CUs with 104 units vs 28.
// Also: diag-only causal mask (wave-uniform branch; ~94% of tiles skip it).
__global__ __launch_bounds__(256)
void attn_kernel(const short* __restrict__ Qb, const short* __restrict__ Kb,
                 const short* __restrict__ Vt, short* __restrict__ AO)
{
  __shared__ __align__(16) short Ks[64 * 128];
  __shared__ __align__(16) short Vs[128 * 64];
  __shared__ __align__(16) short Ps[4][16 * 64];
  const int tid  = threadIdx.x;
  const int wave = tid >> 6, lane = tid & 63;
  const int ln = lane & 15, g = lane >> 4;
  const int bid = blockIdx.x;
  const int bh  = bid & 31;
  const int grp = bid >> 5;
  const int go  = grp & 7;
  int yt;
  switch (grp >> 3) {
    case 0:  yt = go;      break;
    case 1:  yt = 15 - go; break;
    case 2:  yt = 16 + go; break;
    default: yt = 31 - go; break;
  }
  const int qw = yt * 64 + wave * 16;

  bf16x8 qf[4];
#pragma unroll
  for (int ks = 0; ks < 4; ++ks)
    qf[ks] = *(const bf16x8*)&Qb[((size_t)bh * S_LEN + qw + ln) * HDIM + ks * 32 + g * 8];

  f32x4 o[8] = {};
  float m_e[4], l_e[4];
#pragma unroll
  for (int e = 0; e < 4; ++e) { m_e[e] = -3.0e38f; l_e[e] = 0.f; }

  for (int kvt = 0; kvt <= yt; ++kvt) {
    const int kv0 = kvt * 64;
    __syncthreads();
#pragma unroll
    for (int p = 0; p < 4; ++p) {
      const int gi = tid + p * 256;
      {  // K tile [64][128], row-XOR-swizzled
        const int row = gi >> 4, c8 = gi & 15;
        bf16x8 v = *(const bf16x8*)&Kb[((size_t)bh * S_LEN + kv0 + row) * HDIM + c8 * 8];
        *(bf16x8*)&Ks[(row * 128 + c8 * 8) ^ ((row & 7) << 3)] = v;
      }
      {  // V tile as [d=128][kv=64]
        const int dr = gi >> 3, cg = gi & 7;
        bf16x8 v = *(const bf16x8*)&Vt[((size_t)bh * HDIM + dr) * S_LEN + kv0 + cg * 8];
        *(bf16x8*)&Vs[(dr * 64 + cg * 8) ^ ((dr & 7) << 3)] = v;
      }
    }
    __syncthreads();

    // S = Q K^T  (exp2 domain: Q carries scale*log2e)
    f32x4 sfr[4] = {};
#pragma unroll
    for (int ks = 0; ks < 4; ++ks) {
#pragma unroll
      for (int nt = 0; nt < 4; ++nt) {
        const int row = nt * 16 + ln;
        bf16x8 kf = *(const bf16x8*)&Ks[(row * 128 + ks * 32 + g * 8) ^ ((ln & 7) << 3)];
        sfr[nt] = __builtin_amdgcn_mfma_f32_16x16x32_bf16(qf[ks], kf, sfr[nt], 0, 0, 0);
      }
    }

    // causal mask only on the diagonal tile (wave-uniform branch)
    if (kvt == yt) {
#pragma unroll
      for (int e = 0; e < 4; ++e) {
        const int q = qw + 4 * g + e;
#pragma unroll
        for (int nt = 0; nt < 4; ++nt)
          if (kv0 + nt * 16 + ln > q) sfr[nt][e] = -3.0e38f;
      }
    }

    // row-max
    float rmax_e[4];
#pragma unroll
    for (int e = 0; e < 4; ++e) {
      float rmax = fmaxf(fmaxf(sfr[0][e], sfr[1][e]), fmaxf(sfr[2][e], sfr[3][e]));
#pragma unroll
      for (int msk = 1; msk < 16; msk <<= 1)
        rmax = fmaxf(rmax, __shfl_xor(rmax, msk));
      rmax_e[e] = rmax;
    }

    // wave-uniform defer-rescale: pay corr+o-rescale only when max grew >8.
    bool grow = false;
#pragma unroll
    for (int e = 0; e < 4; ++e) grow |= (rmax_e[e] > m_e[e] + 8.0f);
    if (__any(grow)) {
#pragma unroll
      for (int e = 0; e < 4; ++e) {
        const float nm = fmaxf(m_e[e], rmax_e[e]);
        const float corr = exp2f(m_e[e] - nm);
        m_e[e] = nm;
        l_e[e] *= corr;
#pragma unroll
        for (int nt2 = 0; nt2 < 8; ++nt2) o[nt2][e] *= corr;
      }
    }

    // P = exp2(S - m) (bounded by 2^8 when deferred); lane-local l partials
#pragma unroll
    for (int e = 0; e < 4; ++e) {
      float psum = 0.f;
#pragma unroll
      for (int nt = 0; nt < 4; ++nt) {
        const float pv = exp2f(sfr[nt][e] - m_e[e]);
        sfr[nt][e] = pv;
        psum += pv;
      }
      l_e[e] += psum;
    }

    // P -> per-wave LDS (C-layout -> A-layout), swizzled
    short* pw = &Ps[wave][0];
#pragma unroll
    for (int e = 0; e < 4; ++e) {
      const int r = 4 * g + e;
#pragma unroll
      for (int nt = 0; nt < 4; ++nt) {
        const int cc = nt * 16 + ln;
        pw[(r * 64 + cc) ^ ((r & 7) << 3)] = f2bf(sfr[nt][e]);
      }
    }
    __syncthreads();

    // O += P V
#pragma unroll
    for (int ks2 = 0; ks2 < 2; ++ks2) {
      bf16x8 pa = *(const bf16x8*)&pw[(ln * 64 + ks2 * 32 + g * 8) ^ ((ln & 7) << 3)];
#pragma unroll
      for (int nt2 = 0; nt2 < 8; ++nt2) {
        const int row = nt2 * 16 + ln;
        bf16x8 vb = *(const bf16x8*)&Vs[(row * 64 + ks2 * 32 + g * 8) ^ ((ln & 7) << 3)];
        o[nt2] = __builtin_amdgcn_mfma_f32_16x16x32_bf16(pa, vb, o[nt2], 0, 0, 0);
      }
    }
  }

  // epilogue: reduce l, normalize, write
  const int b = bh >> 4, h = bh & 15;
#pragma unroll
  for (int e = 0; e < 4; ++e) {
    float l = l_e[e];
#pragma unroll
    for (int msk = 1; msk < 16; msk <<= 1)
      l += __shfl_xor(l, msk);
    const float inv = 1.0f / l;
    const int q = qw + 4 * g + e;
    short* dst = &AO[((size_t)b * S_LEN + q) * HID + h * HDIM];
#pragma unroll
    for (int nt2 = 0; nt2 < 8; ++nt2)
      dst[nt2 * 16 + ln] = f2bf(o[nt2][e] * inv);
  }
}

extern "C" void kernel_launch(void* const* d_in, const int* in_sizes, int n_in,
                              void* d_out, int out_size, void* d_ws, size_t ws_size,
                              hipStream_t stream)
{
  const float* hs = (const float*)d_in[0];
  const float* wq = (const float*)d_in[1];
  const float* bq = (const float*)d_in[2];
  const float* wk = (const float*)d_in[3];
  const float* bk = (const float*)d_in[4];
  const float* wv = (const float*)d_in[5];
  const float* bv = (const float*)d_in[6];
  const float* wo = (const float*)d_in[7];
  const float* bo = (const float*)d_in[8];
  const int*  pos = (const int*)d_in[10];
  float* out = (float*)d_out;

  const size_t TSZ = (size_t)BATCH * NHEAD * S_LEN * HDIM;  // 8388608 elems
  short* Qb   = (short*)d_ws;
  short* Kb   = Qb + TSZ;
  short* Vt   = Kb + TSZ;
  short* hsb  = Vt + TSZ;        // hs bf16; reused as AO after QKV GEMM
  short* AO   = hsb;
  short* Wqkv = hsb + TSZ;
  short* wob  = Wqkv + 12582912;

  convert_all<<<12288, 256, 0, stream>>>(hs, wq, wk, wv, wo, hsb, Wqkv, wob);
  gemm128<0><<<dim3(32, 48), 256, 0, stream>>>(hsb, Wqkv, bq, bk, bv, Qb, Kb, Vt);
  rope_kernel<<<(BATCH * NHEAD * S_LEN) / 4, 256, 0, stream>>>(Qb, Kb, pos);
  attn_kernel<<<1024, 256, 0, stream>>>(Qb, Kb, Vt, AO);
  gemm128<1><<<dim3(32, 16), 256, 0, stream>>>(AO, wob, bo, nullptr, nullptr, out, nullptr, nullptr);
}

// Round 14
// 290.128 us; speedup vs baseline: 1.1279x; 1.1279x over previous
//
#include <hip/hip_runtime.h>

#define S_LEN 2048
#define HID   2048
#define NHEAD 16
#define HDIM  128
#define BATCH 2
#define KDIM  2048

using bf16x8  = __attribute__((ext_vector_type(8))) short;
using f32x4   = __attribute__((ext_vector_type(4))) float;
using short4v = __attribute__((ext_vector_type(4))) short;

__device__ __forceinline__ short f2bf(float f) {
  union { float f; unsigned u; } v; v.f = f;
  unsigned r = v.u + 0x7fffu + ((v.u >> 16) & 1u);
  return (short)(r >> 16);
}
__device__ __forceinline__ float bf2f(short s) {
  union { unsigned u; float f; } v;
  v.u = ((unsigned)(unsigned short)s) << 16;
  return v.f;
}

// async global->LDS, 16B per lane. LDS dest must be wave-uniform base + lane*16.
__device__ __forceinline__ void gl_lds16(const void* g, void* l) {
  __builtin_amdgcn_global_load_lds(
      (const __attribute__((address_space(1))) void*)g,
      (__attribute__((address_space(3))) void*)l, 16, 0, 0);
}

// ---------------- convert: hs, wq, wk, wv, wo  f32 -> bf16 -------------------
__global__ __launch_bounds__(256)
void convert_all(const float* __restrict__ hs, const float* __restrict__ wq,
                 const float* __restrict__ wk, const float* __restrict__ wv,
                 const float* __restrict__ wo,
                 short* __restrict__ hsb, short* __restrict__ wqkv,
                 short* __restrict__ wob)
{
  int i = blockIdx.x * 256 + threadIdx.x;
  const float* src; short* dst; int j = i;
  if (j < 1048576)      { src = hs; dst = hsb; }
  else if (j < 1572864) { j -= 1048576; src = wq; dst = wqkv; }
  else if (j < 2097152) { j -= 1572864; src = wk; dst = wqkv + 4194304; }
  else if (j < 2621440) { j -= 2097152; src = wv; dst = wqkv + 8388608; }
  else                  { j -= 2621440; src = wo; dst = wob; }
  f32x4 a = ((const f32x4*)src)[2 * j];
  f32x4 b = ((const f32x4*)src)[2 * j + 1];
  bf16x8 o;
  o[0]=f2bf(a[0]); o[1]=f2bf(a[1]); o[2]=f2bf(a[2]); o[3]=f2bf(a[3]);
  o[4]=f2bf(b[0]); o[5]=f2bf(b[1]); o[6]=f2bf(b[2]); o[7]=f2bf(b[3]);
  ((bf16x8*)dst)[j] = o;
}

// ---------------- bf16 GEMM, C = A @ B^T + bias (BK=64, swizzled; r11) -------
template<int KIND>
__global__ __launch_bounds__(256)
void gemm128(const short* __restrict__ A, const short* __restrict__ B,
             const float* __restrict__ bias0, const float* __restrict__ bias1,
             const float* __restrict__ bias2,
             void* __restrict__ O0, void* __restrict__ O1, void* __restrict__ O2)
{
  __shared__ __align__(16) short As[128 * 64];
  __shared__ __align__(16) short Bs[128 * 64];
  const int tid  = threadIdx.x;
  const int lane = tid & 63, wave = tid >> 6;
  const int ln = lane & 15, g = lane >> 4;
  const int wr = wave >> 1, wc = wave & 1;
  const int m0 = blockIdx.x * 128, n0 = blockIdx.y * 128;

  const int srow   = tid >> 3;
  const int schunk = (tid & 7) ^ (srow & 7);
  const short* aS = A + (size_t)(m0 + srow) * KDIM + schunk * 8;
  const short* bS = B + (size_t)(n0 + srow) * KDIM + schunk * 8;

  f32x4 acc[4][4] = {};

  for (int k0 = 0; k0 < KDIM; k0 += 64) {
    __syncthreads();
#pragma unroll
    for (int j = 0; j < 4; ++j) {
      gl_lds16(aS + k0 + j * (32 * KDIM), &As[j * 2048 + tid * 8]);
      gl_lds16(bS + k0 + j * (32 * KDIM), &Bs[j * 2048 + tid * 8]);
    }
    __syncthreads();

#pragma unroll
    for (int ks = 0; ks < 2; ++ks) {
      bf16x8 af[4], bfm[4];
#pragma unroll
      for (int i = 0; i < 4; ++i) {
        const int r = wr * 64 + i * 16 + ln;
        af[i] = *(const bf16x8*)&As[r * 64 + (((ks * 4 + g) ^ (r & 7)) << 3)];
      }
#pragma unroll
      for (int j2 = 0; j2 < 4; ++j2) {
        const int r = wc * 64 + j2 * 16 + ln;
        bfm[j2] = *(const bf16x8*)&Bs[r * 64 + (((ks * 4 + g) ^ (r & 7)) << 3)];
      }
#pragma unroll
      for (int i = 0; i < 4; ++i)
#pragma unroll
        for (int j2 = 0; j2 < 4; ++j2)
          acc[i][j2] = __builtin_amdgcn_mfma_f32_16x16x32_bf16(af[i], bfm[j2], acc[i][j2], 0, 0, 0);
    }
  }

  if constexpr (KIND == 0) {
    const int seg   = n0 >> 11;
    const int nbase = (n0 & 2047) + wc * 64;
    const float* bias = (seg == 0) ? bias0 : (seg == 1) ? bias1 : bias2;
    float bvv[4];
#pragma unroll
    for (int j = 0; j < 4; ++j) bvv[j] = bias[nbase + j * 16 + ln];
    if (seg < 2) {           // Q,K -> [b][h][s][d] bf16
      short* C = (short*)(seg ? O1 : O0);
#pragma unroll
      for (int i = 0; i < 4; ++i) {
        const int mb = m0 + wr * 64 + i * 16 + 4 * g;
#pragma unroll
        for (int j = 0; j < 4; ++j) {
          const int nl = nbase + j * 16 + ln;
          const int h = nl >> 7, d = nl & 127;
#pragma unroll
          for (int e = 0; e < 4; ++e) {
            const int m = mb + e, bb = m >> 11, t = m & (S_LEN - 1);
            C[((size_t)((bb * NHEAD + h) * S_LEN + t) << 7) + d] = f2bf(acc[i][j][e] + bvv[j]);
          }
        }
      }
    } else {                 // V -> transposed [b][h][d][s] bf16
      short* C = (short*)O2;
#pragma unroll
      for (int i = 0; i < 4; ++i) {
        const int mb = m0 + wr * 64 + i * 16 + 4 * g;
        const int bb = mb >> 11, t0 = mb & (S_LEN - 1);
#pragma unroll
        for (int j = 0; j < 4; ++j) {
          const int nl = nbase + j * 16 + ln;
          const int h = nl >> 7, d = nl & 127;
          short4v v;
#pragma unroll
          for (int e = 0; e < 4; ++e) v[e] = f2bf(acc[i][j][e] + bvv[j]);
          *(short4v*)&C[((size_t)((bb * NHEAD + h) * HDIM + d)) * S_LEN + t0] = v;
        }
      }
    }
  } else {                   // O-proj -> f32
    float* C = (float*)O0;
    float bvv[4];
#pragma unroll
    for (int j = 0; j < 4; ++j) bvv[j] = bias0[n0 + wc * 64 + j * 16 + ln];
#pragma unroll
    for (int i = 0; i < 4; ++i) {
      const int mb = m0 + wr * 64 + i * 16 + 4 * g;
#pragma unroll
      for (int j = 0; j < 4; ++j) {
        const int n = n0 + wc * 64 + j * 16 + ln;
#pragma unroll
        for (int e = 0; e < 4; ++e)
          C[(size_t)(mb + e) * HID + n] = acc[i][j][e] + bvv[j];
      }
    }
  }
}

// ---------------- RoPE in-place on Q,K ([b][h][s][d] bf16) -------------------
// Q additionally pre-scaled by 1/sqrt(HD)*log2(e): softmax runs in exp2 domain.
#define QSCALE 0.12752767502f   // (1/sqrt(128)) * log2(e)
__global__ __launch_bounds__(256)
void rope_kernel(short* __restrict__ Qb, short* __restrict__ Kb,
                 const int* __restrict__ pos_ids)
{
  const int row = blockIdx.x * 4 + (threadIdx.x >> 6);
  const int d   = threadIdx.x & 63;
  const int bh  = row >> 11, t = row & (S_LEN - 1);
  const int b   = bh >> 4;
  const float pos = (float)pos_ids[b * S_LEN + t];
  const float inv = powf(10000.0f, -(float)d * (1.0f / 64.0f));
  float s, c;
  sincosf(pos * inv, &s, &c);
  const size_t base = (size_t)row * HDIM;
  {
    float x1 = bf2f(Qb[base + d]), x2 = bf2f(Qb[base + d + 64]);
    Qb[base + d]      = f2bf((x1 * c - x2 * s) * QSCALE);
    Qb[base + d + 64] = f2bf((x2 * c + x1 * s) * QSCALE);
  }
  {
    float x1 = bf2f(Kb[base + d]), x2 = bf2f(Kb[base + d + 64]);
    Kb[base + d]      = f2bf(x1 * c - x2 * s);
    Kb[base + d + 64] = f2bf(x2 * c + x1 * s);
  }
}

// ---------------- flash attention ------------------------------------------
// EXACT round-12 code (89 us, <=128 VGPR) with ONE line changed: the grp->yt
// map is now CU-quad-balanced and BRANCHLESS. Co-resident quads on a CU are
// groups {G, G+8, G+16, G+24} (bids b, b+256, b+512, b+768); mapping them to
// yts {G, 15-G, 16+G, 31-G} makes per-CU iter sum = 66 for every G (old
// zigzag gave some CUs 104 units vs 28). Bijective; same-bh-per-CU retained.
__global__ __launch_bounds__(256)
void attn_kernel(const short* __restrict__ Qb, const short* __restrict__ Kb,
                 const short* __restrict__ Vt, short* __restrict__ AO)
{
  __shared__ __align__(16) short Ks[64 * 128];
  __shared__ __align__(16) short Vs[128 * 64];
  __shared__ __align__(16) short Ps[4][16 * 64];
  const int tid  = threadIdx.x;
  const int wave = tid >> 6, lane = tid & 63;
  const int ln = lane & 15, g = lane >> 4;
  const int bid = blockIdx.x;
  const int bh  = bid & 31;
  const int grp = bid >> 5;
  const int yt  = (grp & 16) + ((grp & 7) ^ ((grp & 8) ? 15 : 0));
  const int qw  = yt * 64 + wave * 16;

  bf16x8 qf[4];
#pragma unroll
  for (int ks = 0; ks < 4; ++ks)
    qf[ks] = *(const bf16x8*)&Qb[((size_t)bh * S_LEN + qw + ln) * HDIM + ks * 32 + g * 8];

  f32x4 o[8] = {};
  float m_e[4], l_e[4];
#pragma unroll
  for (int e = 0; e < 4; ++e) { m_e[e] = -3.0e38f; l_e[e] = 0.f; }

  for (int kvt = 0; kvt <= yt; ++kvt) {
    const int kv0 = kvt * 64;
    __syncthreads();
#pragma unroll
    for (int p = 0; p < 4; ++p) {
      const int gi = tid + p * 256;
      {  // K tile [64][128], row-XOR-swizzled
        const int row = gi >> 4, c8 = gi & 15;
        bf16x8 v = *(const bf16x8*)&Kb[((size_t)bh * S_LEN + kv0 + row) * HDIM + c8 * 8];
        *(bf16x8*)&Ks[(row * 128 + c8 * 8) ^ ((row & 7) << 3)] = v;
      }
      {  // V tile as [d=128][kv=64]
        const int dr = gi >> 3, cg = gi & 7;
        bf16x8 v = *(const bf16x8*)&Vt[((size_t)bh * HDIM + dr) * S_LEN + kv0 + cg * 8];
        *(bf16x8*)&Vs[(dr * 64 + cg * 8) ^ ((dr & 7) << 3)] = v;
      }
    }
    __syncthreads();

    // S = Q K^T  (exp2 domain: Q carries scale*log2e)
    f32x4 sfr[4] = {};
#pragma unroll
    for (int ks = 0; ks < 4; ++ks) {
#pragma unroll
      for (int nt = 0; nt < 4; ++nt) {
        const int row = nt * 16 + ln;
        bf16x8 kf = *(const bf16x8*)&Ks[(row * 128 + ks * 32 + g * 8) ^ ((ln & 7) << 3)];
        sfr[nt] = __builtin_amdgcn_mfma_f32_16x16x32_bf16(qf[ks], kf, sfr[nt], 0, 0, 0);
      }
    }

    // causal mask + row-max (fused, as in r12)
    float rmax_e[4];
#pragma unroll
    for (int e = 0; e < 4; ++e) {
      const int q = qw + 4 * g + e;
      float rmax = -3.0e38f;
#pragma unroll
      for (int nt = 0; nt < 4; ++nt) {
        float v = sfr[nt][e];
        if (kv0 + nt * 16 + ln > q) v = -3.0e38f;
        sfr[nt][e] = v;
        rmax = fmaxf(rmax, v);
      }
#pragma unroll
      for (int msk = 1; msk < 16; msk <<= 1)
        rmax = fmaxf(rmax, __shfl_xor(rmax, msk));
      rmax_e[e] = rmax;
    }

    // wave-uniform defer-rescale: only pay corr+o-rescale when max grew >8.
    bool grow = false;
#pragma unroll
    for (int e = 0; e < 4; ++e) grow |= (rmax_e[e] > m_e[e] + 8.0f);
    if (__any(grow)) {
#pragma unroll
      for (int e = 0; e < 4; ++e) {
        const float nm = fmaxf(m_e[e], rmax_e[e]);
        const float corr = exp2f(m_e[e] - nm);
        m_e[e] = nm;
        l_e[e] *= corr;
#pragma unroll
        for (int nt2 = 0; nt2 < 8; ++nt2) o[nt2][e] *= corr;
      }
    }

    // P = exp2(S - m) (bounded by 2^8 when deferred); lane-local l partials
#pragma unroll
    for (int e = 0; e < 4; ++e) {
      float psum = 0.f;
#pragma unroll
      for (int nt = 0; nt < 4; ++nt) {
        const float pv = exp2f(sfr[nt][e] - m_e[e]);
        sfr[nt][e] = pv;
        psum += pv;
      }
      l_e[e] += psum;
    }

    // P -> per-wave LDS (C-layout -> A-layout), swizzled
    short* pw = &Ps[wave][0];
#pragma unroll
    for (int e = 0; e < 4; ++e) {
      const int r = 4 * g + e;
#pragma unroll
      for (int nt = 0; nt < 4; ++nt) {
        const int cc = nt * 16 + ln;
        pw[(r * 64 + cc) ^ ((r & 7) << 3)] = f2bf(sfr[nt][e]);
      }
    }
    __syncthreads();

    // O += P V
#pragma unroll
    for (int ks2 = 0; ks2 < 2; ++ks2) {
      bf16x8 pa = *(const bf16x8*)&pw[(ln * 64 + ks2 * 32 + g * 8) ^ ((ln & 7) << 3)];
#pragma unroll
      for (int nt2 = 0; nt2 < 8; ++nt2) {
        const int row = nt2 * 16 + ln;
        bf16x8 vb = *(const bf16x8*)&Vs[(row * 64 + ks2 * 32 + g * 8) ^ ((ln & 7) << 3)];
        o[nt2] = __builtin_amdgcn_mfma_f32_16x16x32_bf16(pa, vb, o[nt2], 0, 0, 0);
      }
    }
  }

  // epilogue: reduce l, normalize, write
  const int b = bh >> 4, h = bh & 15;
#pragma unroll
  for (int e = 0; e < 4; ++e) {
    float l = l_e[e];
#pragma unroll
    for (int msk = 1; msk < 16; msk <<= 1)
      l += __shfl_xor(l, msk);
    const float inv = 1.0f / l;
    const int q = qw + 4 * g + e;
    short* dst = &AO[((size_t)b * S_LEN + q) * HID + h * HDIM];
#pragma unroll
    for (int nt2 = 0; nt2 < 8; ++nt2)
      dst[nt2 * 16 + ln] = f2bf(o[nt2][e] * inv);
  }
}

extern "C" void kernel_launch(void* const* d_in, const int* in_sizes, int n_in,
                              void* d_out, int out_size, void* d_ws, size_t ws_size,
                              hipStream_t stream)
{
  const float* hs = (const float*)d_in[0];
  const float* wq = (const float*)d_in[1];
  const float* bq = (const float*)d_in[2];
  const float* wk = (const float*)d_in[3];
  const float* bk = (const float*)d_in[4];
  const float* wv = (const float*)d_in[5];
  const float* bv = (const float*)d_in[6];
  const float* wo = (const float*)d_in[7];
  const float* bo = (const float*)d_in[8];
  const int*  pos = (const int*)d_in[10];
  float* out = (float*)d_out;

  const size_t TSZ = (size_t)BATCH * NHEAD * S_LEN * HDIM;  // 8388608 elems
  short* Qb   = (short*)d_ws;
  short* Kb   = Qb + TSZ;
  short* Vt   = Kb + TSZ;
  short* hsb  = Vt + TSZ;        // hs bf16; reused as AO after QKV GEMM
  short* AO   = hsb;
  short* Wqkv = hsb + TSZ;
  short* wob  = Wqkv + 12582912;

  convert_all<<<12288, 256, 0, stream>>>(hs, wq, wk, wv, wo, hsb, Wqkv, wob);
  gemm128<0><<<dim3(32, 48), 256, 0, stream>>>(hsb, Wqkv, bq, bk, bv, Qb, Kb, Vt);
  rope_kernel<<<(BATCH * NHEAD * S_LEN) / 4, 256, 0, stream>>>(Qb, Kb, pos);
  attn_kernel<<<1024, 256, 0, stream>>>(Qb, Kb, Vt, AO);
  gemm128<1><<<dim3(32, 16), 256, 0, stream>>>(AO, wob, bo, nullptr, nullptr, out, nullptr, nullptr);
}

// Round 15
// 275.346 us; speedup vs baseline: 1.1884x; 1.0537x over previous
//
#include <hip/hip_runtime.h>

#define S_LEN 2048
#define HID   2048
#define NHEAD 16
#define HDIM  128
#define BATCH 2
#define KDIM  2048

using bf16x8  = __attribute__((ext_vector_type(8))) short;
using f32x4   = __attribute__((ext_vector_type(4))) float;
using short4v = __attribute__((ext_vector_type(4))) short;

__device__ __forceinline__ short f2bf(float f) {
  union { float f; unsigned u; } v; v.f = f;
  unsigned r = v.u + 0x7fffu + ((v.u >> 16) & 1u);
  return (short)(r >> 16);
}
__device__ __forceinline__ float bf2f(short s) {
  union { unsigned u; float f; } v;
  v.u = ((unsigned)(unsigned short)s) << 16;
  return v.f;
}

// async global->LDS, 16B per lane. LDS dest must be wave-uniform base + lane*16.
__device__ __forceinline__ void gl_lds16(const void* g, void* l) {
  __builtin_amdgcn_global_load_lds(
      (const __attribute__((address_space(1))) void*)g,
      (__attribute__((address_space(3))) void*)l, 16, 0, 0);
}

// ---------------- convert: hs, wq, wk, wv, wo  f32 -> bf16 -------------------
__global__ __launch_bounds__(256)
void convert_all(const float* __restrict__ hs, const float* __restrict__ wq,
                 const float* __restrict__ wk, const float* __restrict__ wv,
                 const float* __restrict__ wo,
                 short* __restrict__ hsb, short* __restrict__ wqkv,
                 short* __restrict__ wob)
{
  int i = blockIdx.x * 256 + threadIdx.x;
  const float* src; short* dst; int j = i;
  if (j < 1048576)      { src = hs; dst = hsb; }
  else if (j < 1572864) { j -= 1048576; src = wq; dst = wqkv; }
  else if (j < 2097152) { j -= 1572864; src = wk; dst = wqkv + 4194304; }
  else if (j < 2621440) { j -= 2097152; src = wv; dst = wqkv + 8388608; }
  else                  { j -= 2621440; src = wo; dst = wob; }
  f32x4 a = ((const f32x4*)src)[2 * j];
  f32x4 b = ((const f32x4*)src)[2 * j + 1];
  bf16x8 o;
  o[0]=f2bf(a[0]); o[1]=f2bf(a[1]); o[2]=f2bf(a[2]); o[3]=f2bf(a[3]);
  o[4]=f2bf(b[0]); o[5]=f2bf(b[1]); o[6]=f2bf(b[2]); o[7]=f2bf(b[3]);
  ((bf16x8*)dst)[j] = o;
}

// ---------------- bf16 GEMM, C = A @ B^T + bias (BK=64, swizzled; r11) -------
template<int KIND>
__global__ __launch_bounds__(256)
void gemm128(const short* __restrict__ A, const short* __restrict__ B,
             const float* __restrict__ bias0, const float* __restrict__ bias1,
             const float* __restrict__ bias2,
             void* __restrict__ O0, void* __restrict__ O1, void* __restrict__ O2)
{
  __shared__ __align__(16) short As[128 * 64];
  __shared__ __align__(16) short Bs[128 * 64];
  const int tid  = threadIdx.x;
  const int lane = tid & 63, wave = tid >> 6;
  const int ln = lane & 15, g = lane >> 4;
  const int wr = wave >> 1, wc = wave & 1;
  const int m0 = blockIdx.x * 128, n0 = blockIdx.y * 128;

  const int srow   = tid >> 3;
  const int schunk = (tid & 7) ^ (srow & 7);
  const short* aS = A + (size_t)(m0 + srow) * KDIM + schunk * 8;
  const short* bS = B + (size_t)(n0 + srow) * KDIM + schunk * 8;

  f32x4 acc[4][4] = {};

  for (int k0 = 0; k0 < KDIM; k0 += 64) {
    __syncthreads();
#pragma unroll
    for (int j = 0; j < 4; ++j) {
      gl_lds16(aS + k0 + j * (32 * KDIM), &As[j * 2048 + tid * 8]);
      gl_lds16(bS + k0 + j * (32 * KDIM), &Bs[j * 2048 + tid * 8]);
    }
    __syncthreads();

#pragma unroll
    for (int ks = 0; ks < 2; ++ks) {
      bf16x8 af[4], bfm[4];
#pragma unroll
      for (int i = 0; i < 4; ++i) {
        const int r = wr * 64 + i * 16 + ln;
        af[i] = *(const bf16x8*)&As[r * 64 + (((ks * 4 + g) ^ (r & 7)) << 3)];
      }
#pragma unroll
      for (int j2 = 0; j2 < 4; ++j2) {
        const int r = wc * 64 + j2 * 16 + ln;
        bfm[j2] = *(const bf16x8*)&Bs[r * 64 + (((ks * 4 + g) ^ (r & 7)) << 3)];
      }
#pragma unroll
      for (int i = 0; i < 4; ++i)
#pragma unroll
        for (int j2 = 0; j2 < 4; ++j2)
          acc[i][j2] = __builtin_amdgcn_mfma_f32_16x16x32_bf16(af[i], bfm[j2], acc[i][j2], 0, 0, 0);
    }
  }

  if constexpr (KIND == 0) {
    const int seg   = n0 >> 11;
    const int nbase = (n0 & 2047) + wc * 64;
    const float* bias = (seg == 0) ? bias0 : (seg == 1) ? bias1 : bias2;
    float bvv[4];
#pragma unroll
    for (int j = 0; j < 4; ++j) bvv[j] = bias[nbase + j * 16 + ln];
    if (seg < 2) {           // Q,K -> [b][h][s][d] bf16
      short* C = (short*)(seg ? O1 : O0);
#pragma unroll
      for (int i = 0; i < 4; ++i) {
        const int mb = m0 + wr * 64 + i * 16 + 4 * g;
#pragma unroll
        for (int j = 0; j < 4; ++j) {
          const int nl = nbase + j * 16 + ln;
          const int h = nl >> 7, d = nl & 127;
#pragma unroll
          for (int e = 0; e < 4; ++e) {
            const int m = mb + e, bb = m >> 11, t = m & (S_LEN - 1);
            C[((size_t)((bb * NHEAD + h) * S_LEN + t) << 7) + d] = f2bf(acc[i][j][e] + bvv[j]);
          }
        }
      }
    } else {                 // V -> transposed [b][h][d][s] bf16
      short* C = (short*)O2;
#pragma unroll
      for (int i = 0; i < 4; ++i) {
        const int mb = m0 + wr * 64 + i * 16 + 4 * g;
        const int bb = mb >> 11, t0 = mb & (S_LEN - 1);
#pragma unroll
        for (int j = 0; j < 4; ++j) {
          const int nl = nbase + j * 16 + ln;
          const int h = nl >> 7, d = nl & 127;
          short4v v;
#pragma unroll
          for (int e = 0; e < 4; ++e) v[e] = f2bf(acc[i][j][e] + bvv[j]);
          *(short4v*)&C[((size_t)((bb * NHEAD + h) * HDIM + d)) * S_LEN + t0] = v;
        }
      }
    }
  } else {                   // O-proj -> f32
    float* C = (float*)O0;
    float bvv[4];
#pragma unroll
    for (int j = 0; j < 4; ++j) bvv[j] = bias0[n0 + wc * 64 + j * 16 + ln];
#pragma unroll
    for (int i = 0; i < 4; ++i) {
      const int mb = m0 + wr * 64 + i * 16 + 4 * g;
#pragma unroll
      for (int j = 0; j < 4; ++j) {
        const int n = n0 + wc * 64 + j * 16 + ln;
#pragma unroll
        for (int e = 0; e < 4; ++e)
          C[(size_t)(mb + e) * HID + n] = acc[i][j][e] + bvv[j];
      }
    }
  }
}

// ---------------- RoPE in-place on Q,K ([b][h][s][d] bf16) -------------------
// Q additionally pre-scaled by 1/sqrt(HD)*log2(e): softmax runs in exp2 domain.
#define QSCALE 0.12752767502f   // (1/sqrt(128)) * log2(e)
__global__ __launch_bounds__(256)
void rope_kernel(short* __restrict__ Qb, short* __restrict__ Kb,
                 const int* __restrict__ pos_ids)
{
  const int row = blockIdx.x * 4 + (threadIdx.x >> 6);
  const int d   = threadIdx.x & 63;
  const int bh  = row >> 11, t = row & (S_LEN - 1);
  const int b   = bh >> 4;
  const float pos = (float)pos_ids[b * S_LEN + t];
  const float inv = powf(10000.0f, -(float)d * (1.0f / 64.0f));
  float s, c;
  sincosf(pos * inv, &s, &c);
  const size_t base = (size_t)row * HDIM;
  {
    float x1 = bf2f(Qb[base + d]), x2 = bf2f(Qb[base + d + 64]);
    Qb[base + d]      = f2bf((x1 * c - x2 * s) * QSCALE);
    Qb[base + d + 64] = f2bf((x2 * c + x1 * s) * QSCALE);
  }
  {
    float x1 = bf2f(Kb[base + d]), x2 = bf2f(Kb[base + d + 64]);
    Kb[base + d]      = f2bf(x1 * c - x2 * s);
    Kb[base + d + 64] = f2bf(x2 * c + x1 * s);
  }
}

// ---------------- flash attention ------------------------------------------
// r12/r14 per-thread structure UNCHANGED (protects the 128-VGPR cliff), but
// QBLK 64 -> 128: 8 waves / 512 threads per block, each wave still 16 q-rows.
// Halves (block,iter) pairs => half the K/V staging bytes, half the barrier
// count, half the K/V L2 re-reads, same MFMA work. LDS = Ks16+Vs16+Ps16 =
// 48 KB, 2 blocks/CU = 16 waves/CU (same as before). Grid 512 = 32 bh x 16
// q-tiles; co-resident pairs {G, G+8} -> yts {G, 15-G}, iter sum 34 = const.
__global__ __launch_bounds__(512)
void attn_kernel(const short* __restrict__ Qb, const short* __restrict__ Kb,
                 const short* __restrict__ Vt, short* __restrict__ AO)
{
  __shared__ __align__(16) short Ks[64 * 128];
  __shared__ __align__(16) short Vs[128 * 64];
  __shared__ __align__(16) short Ps[8][16 * 64];
  const int tid  = threadIdx.x;
  const int wave = tid >> 6, lane = tid & 63;
  const int ln = lane & 15, g = lane >> 4;
  const int bid = blockIdx.x;
  const int bh  = bid & 31;
  const int grp = bid >> 5;                      // 0..15
  const int yt  = (grp & 7) ^ ((grp & 8) ? 15 : 0);   // pairs {G,15-G}
  const int qw  = yt * 128 + wave * 16;

  bf16x8 qf[4];
#pragma unroll
  for (int ks = 0; ks < 4; ++ks)
    qf[ks] = *(const bf16x8*)&Qb[((size_t)bh * S_LEN + qw + ln) * HDIM + ks * 32 + g * 8];

  f32x4 o[8] = {};
  float m_e[4], l_e[4];
#pragma unroll
  for (int e = 0; e < 4; ++e) { m_e[e] = -3.0e38f; l_e[e] = 0.f; }

  const int kvt_max = 2 * yt + 1;   // covers q rows yt*128 .. yt*128+127
  for (int kvt = 0; kvt <= kvt_max; ++kvt) {
    const int kv0 = kvt * 64;
    __syncthreads();
#pragma unroll
    for (int p = 0; p < 2; ++p) {
      const int gi = tid + p * 512;
      {  // K tile [64][128], row-XOR-swizzled
        const int row = gi >> 4, c8 = gi & 15;
        bf16x8 v = *(const bf16x8*)&Kb[((size_t)bh * S_LEN + kv0 + row) * HDIM + c8 * 8];
        *(bf16x8*)&Ks[(row * 128 + c8 * 8) ^ ((row & 7) << 3)] = v;
      }
      {  // V tile as [d=128][kv=64]
        const int dr = gi >> 3, cg = gi & 7;
        bf16x8 v = *(const bf16x8*)&Vt[((size_t)bh * HDIM + dr) * S_LEN + kv0 + cg * 8];
        *(bf16x8*)&Vs[(dr * 64 + cg * 8) ^ ((dr & 7) << 3)] = v;
      }
    }
    __syncthreads();

    // S = Q K^T  (exp2 domain: Q carries scale*log2e)
    f32x4 sfr[4] = {};
#pragma unroll
    for (int ks = 0; ks < 4; ++ks) {
#pragma unroll
      for (int nt = 0; nt < 4; ++nt) {
        const int row = nt * 16 + ln;
        bf16x8 kf = *(const bf16x8*)&Ks[(row * 128 + ks * 32 + g * 8) ^ ((ln & 7) << 3)];
        sfr[nt] = __builtin_amdgcn_mfma_f32_16x16x32_bf16(qf[ks], kf, sfr[nt], 0, 0, 0);
      }
    }

    // causal mask + row-max (fused, r12 structure)
    float rmax_e[4];
#pragma unroll
    for (int e = 0; e < 4; ++e) {
      const int q = qw + 4 * g + e;
      float rmax = -3.0e38f;
#pragma unroll
      for (int nt = 0; nt < 4; ++nt) {
        float v = sfr[nt][e];
        if (kv0 + nt * 16 + ln > q) v = -3.0e38f;
        sfr[nt][e] = v;
        rmax = fmaxf(rmax, v);
      }
#pragma unroll
      for (int msk = 1; msk < 16; msk <<= 1)
        rmax = fmaxf(rmax, __shfl_xor(rmax, msk));
      rmax_e[e] = rmax;
    }

    // wave-uniform defer-rescale: only pay corr+o-rescale when max grew >8.
    bool grow = false;
#pragma unroll
    for (int e = 0; e < 4; ++e) grow |= (rmax_e[e] > m_e[e] + 8.0f);
    if (__any(grow)) {
#pragma unroll
      for (int e = 0; e < 4; ++e) {
        const float nm = fmaxf(m_e[e], rmax_e[e]);
        const float corr = exp2f(m_e[e] - nm);
        m_e[e] = nm;
        l_e[e] *= corr;
#pragma unroll
        for (int nt2 = 0; nt2 < 8; ++nt2) o[nt2][e] *= corr;
      }
    }

    // P = exp2(S - m) (bounded by 2^8 when deferred); lane-local l partials
#pragma unroll
    for (int e = 0; e < 4; ++e) {
      float psum = 0.f;
#pragma unroll
      for (int nt = 0; nt < 4; ++nt) {
        const float pv = exp2f(sfr[nt][e] - m_e[e]);
        sfr[nt][e] = pv;
        psum += pv;
      }
      l_e[e] += psum;
    }

    // P -> per-wave LDS (C-layout -> A-layout), swizzled
    short* pw = &Ps[wave][0];
#pragma unroll
    for (int e = 0; e < 4; ++e) {
      const int r = 4 * g + e;
#pragma unroll
      for (int nt = 0; nt < 4; ++nt) {
        const int cc = nt * 16 + ln;
        pw[(r * 64 + cc) ^ ((r & 7) << 3)] = f2bf(sfr[nt][e]);
      }
    }
    __syncthreads();

    // O += P V
#pragma unroll
    for (int ks2 = 0; ks2 < 2; ++ks2) {
      bf16x8 pa = *(const bf16x8*)&pw[(ln * 64 + ks2 * 32 + g * 8) ^ ((ln & 7) << 3)];
#pragma unroll
      for (int nt2 = 0; nt2 < 8; ++nt2) {
        const int row = nt2 * 16 + ln;
        bf16x8 vb = *(const bf16x8*)&Vs[(row * 64 + ks2 * 32 + g * 8) ^ ((ln & 7) << 3)];
        o[nt2] = __builtin_amdgcn_mfma_f32_16x16x32_bf16(pa, vb, o[nt2], 0, 0, 0);
      }
    }
  }

  // epilogue: reduce l, normalize, write
  const int b = bh >> 4, h = bh & 15;
#pragma unroll
  for (int e = 0; e < 4; ++e) {
    float l = l_e[e];
#pragma unroll
    for (int msk = 1; msk < 16; msk <<= 1)
      l += __shfl_xor(l, msk);
    const float inv = 1.0f / l;
    const int q = qw + 4 * g + e;
    short* dst = &AO[((size_t)b * S_LEN + q) * HID + h * HDIM];
#pragma unroll
    for (int nt2 = 0; nt2 < 8; ++nt2)
      dst[nt2 * 16 + ln] = f2bf(o[nt2][e] * inv);
  }
}

extern "C" void kernel_launch(void* const* d_in, const int* in_sizes, int n_in,
                              void* d_out, int out_size, void* d_ws, size_t ws_size,
                              hipStream_t stream)
{
  const float* hs = (const float*)d_in[0];
  const float* wq = (const float*)d_in[1];
  const float* bq = (const float*)d_in[2];
  const float* wk = (const float*)d_in[3];
  const float* bk = (const float*)d_in[4];
  const float* wv = (const float*)d_in[5];
  const float* bv = (const float*)d_in[6];
  const float* wo = (const float*)d_in[7];
  const float* bo = (const float*)d_in[8];
  const int*  pos = (const int*)d_in[10];
  float* out = (float*)d_out;

  const size_t TSZ = (size_t)BATCH * NHEAD * S_LEN * HDIM;  // 8388608 elems
  short* Qb   = (short*)d_ws;
  short* Kb   = Qb + TSZ;
  short* Vt   = Kb + TSZ;
  short* hsb  = Vt + TSZ;        // hs bf16; reused as AO after QKV GEMM
  short* AO   = hsb;
  short* Wqkv = hsb + TSZ;
  short* wob  = Wqkv + 12582912;

  convert_all<<<12288, 256, 0, stream>>>(hs, wq, wk, wv, wo, hsb, Wqkv, wob);
  gemm128<0><<<dim3(32, 48), 256, 0, stream>>>(hsb, Wqkv, bq, bk, bv, Qb, Kb, Vt);
  rope_kernel<<<(BATCH * NHEAD * S_LEN) / 4, 256, 0, stream>>>(Qb, Kb, pos);
  attn_kernel<<<512, 512, 0, stream>>>(Qb, Kb, Vt, AO);
  gemm128<1><<<dim3(32, 16), 256, 0, stream>>>(AO, wob, bo, nullptr, nullptr, out, nullptr, nullptr);
}